// Round 1
// baseline (263.211 us; speedup 1.0000x reference)
//
#include <hip/hip_runtime.h>

#define T_LEN 16384
#define CIN   64
#define COUT  64
#define KTAPS 127
#define TN    256          // t-tile per block
#define WPAD  384          // staged window width (TN + 128)
#define WT_KS 4096         // COUT*CIN elems per tap slice

typedef __attribute__((ext_vector_type(8)))  __bf16 bf16x8;
typedef __attribute__((ext_vector_type(16))) float  f32x16;
typedef __attribute__((ext_vector_type(4)))  float  float4v;

__device__ inline unsigned short f2bf(float f) {
    unsigned u = __builtin_bit_cast(unsigned, f);
    u += 0x7fffu + ((u >> 16) & 1u);        // round-to-nearest-even
    return (unsigned short)(u >> 16);
}

// Wt[k'][o][i] = bf16(W[o][i][126-k'])  (reversed taps -> correlation form)
__global__ void wt_transform(const float* __restrict__ W,
                             unsigned short* __restrict__ Wt) {
    int tid = blockIdx.x * 256 + threadIdx.x;
    if (tid >= KTAPS * WT_KS) return;
    int kp   = tid >> 12;          // tap index k'
    int rest = tid & 4095;         // o*64 + i
    int o = rest >> 6, i = rest & 63;
    float w = W[(o * CIN + i) * KTAPS + (126 - kp)];
    Wt[tid] = f2bf(w);
}

__global__ __launch_bounds__(256, 2)
void conv_mfma(const float* __restrict__ x,
               const unsigned short* __restrict__ Wt,
               float* __restrict__ y) {
    // xs[w][cin] bf16, XOR-swizzled: halfword index = w*64 + (cin ^ ((w&7)<<3))
    __shared__ unsigned short xs[WPAD * CIN];   // 48 KB

    const int tid = threadIdx.x;
    const int bb  = blockIdx.x >> 6;      // batch
    const int tt  = blockIdx.x & 63;      // t-tile
    const int t0  = tt * TN;

    // ---- stage x window [t0-64, t0+320) transposed into LDS (bf16, swizzled)
    {
        const int cin  = tid >> 2;            // 0..63
        const int wseg = (tid & 3) * 96;      // 4 segments of 96 w's
        const float* xrow = x + (bb * CIN + cin) * T_LEN + (t0 - 64);
        for (int j = 0; j < 96; j += 4) {
            const int w = wseg + j;
            const int u = t0 - 64 + w;        // global t index (16B aligned)
            float4v v;
            if (u >= 0 && u + 3 < T_LEN) {
                v = *(const float4v*)(xrow + w);
            } else {
                v.x = (u + 0 >= 0 && u + 0 < T_LEN) ? xrow[w + 0] : 0.f;
                v.y = (u + 1 >= 0 && u + 1 < T_LEN) ? xrow[w + 1] : 0.f;
                v.z = (u + 2 >= 0 && u + 2 < T_LEN) ? xrow[w + 2] : 0.f;
                v.w = (u + 3 >= 0 && u + 3 < T_LEN) ? xrow[w + 3] : 0.f;
            }
            #pragma unroll
            for (int e = 0; e < 4; ++e) {
                const int we = w + e;
                const float fv = (e == 0) ? v.x : (e == 1) ? v.y : (e == 2) ? v.z : v.w;
                xs[we * 64 + (cin ^ ((we & 7) << 3))] = f2bf(fv);
            }
        }
    }
    __syncthreads();

    const int lane   = tid & 63;
    const int wv     = tid >> 6;          // wave 0..3
    const int l31    = lane & 31;
    const int kg     = lane >> 5;         // K-half (0/1)
    const int twbase = wv * 64;           // wave's 64-t range

    f32x16 acc[2][2] = {};                // [m: o-tile][n: t-tile]

    // A (W) fragment base: lane row = l31, k-half = kg
    const unsigned short* wp = Wt + l31 * 64 + kg * 8;
    const int brow0 = twbase + l31 + 1;   // LDS row at k'=0 (window offset +1)

    for (int kp = 0; kp < KTAPS; ++kp) {
        const unsigned short* wpk = wp + kp * WT_KS;
        const int w0 = brow0 + kp;                 // row for n=0 (n=1: +32, same w&7)
        const int h  = kg ^ (w0 & 7);              // swizzle term
        const int base0 = w0 * 64;
        #pragma unroll
        for (int cc = 0; cc < 4; ++cc) {           // cin chunks of 16
            const int coff = ((cc << 1) ^ h) << 3; // swizzled halfword col offset
            bf16x8 b0 = *(const bf16x8*)(xs + base0 + coff);
            bf16x8 b1 = *(const bf16x8*)(xs + base0 + 2048 + coff);
            bf16x8 a0 = *(const bf16x8*)(wpk + cc * 16);
            bf16x8 a1 = *(const bf16x8*)(wpk + 2048 + cc * 16);
            acc[0][0] = __builtin_amdgcn_mfma_f32_32x32x16_bf16(a0, b0, acc[0][0], 0, 0, 0);
            acc[0][1] = __builtin_amdgcn_mfma_f32_32x32x16_bf16(a0, b1, acc[0][1], 0, 0, 0);
            acc[1][0] = __builtin_amdgcn_mfma_f32_32x32x16_bf16(a1, b0, acc[1][0], 0, 0, 0);
            acc[1][1] = __builtin_amdgcn_mfma_f32_32x32x16_bf16(a1, b1, acc[1][1], 0, 0, 0);
        }
    }

    // ---- epilogue: D col = lane&31 -> t, row = (r&3)+8*(r>>2)+4*kg -> o
    const int ybase = (bb * COUT) * T_LEN;
    #pragma unroll
    for (int m = 0; m < 2; ++m) {
        #pragma unroll
        for (int n = 0; n < 2; ++n) {
            const int t = t0 + twbase + n * 32 + l31;
            #pragma unroll
            for (int r = 0; r < 16; ++r) {
                const int o = m * 32 + (r & 3) + 8 * (r >> 2) + 4 * kg;
                y[ybase + o * T_LEN + t] = acc[m][n][r];
            }
        }
    }
}

extern "C" void kernel_launch(void* const* d_in, const int* in_sizes, int n_in,
                              void* d_out, int out_size, void* d_ws, size_t ws_size,
                              hipStream_t stream) {
    const float* x = (const float*)d_in[0];
    const float* W = (const float*)d_in[1];
    float* yout = (float*)d_out;
    unsigned short* Wt = (unsigned short*)d_ws;   // 127*4096*2 B ~= 1 MB

    const int total = KTAPS * WT_KS;
    wt_transform<<<(total + 255) / 256, 256, 0, stream>>>(W, Wt);

    const int grid = 8 * (T_LEN / TN);            // 512 blocks
    conv_mfma<<<grid, 256, 0, stream>>>(x, Wt, yout);
}

// Round 2
// 139.747 us; speedup vs baseline: 1.8835x; 1.8835x over previous
//
#include <hip/hip_runtime.h>

#define T_LEN 16384
#define CIN   64
#define COUT  64
#define KTAPS 127
#define TN    256          // t-tile per block
#define WROWS 383          // staged x rows (w = 0..382 used)
#define WT_KS 4096         // COUT*CIN halfwords per tap slice

typedef __attribute__((ext_vector_type(8)))  __bf16 bf16x8;
typedef __attribute__((ext_vector_type(16))) float  f32x16;
typedef __attribute__((ext_vector_type(4)))  float  float4v;

__device__ inline unsigned short f2bf(float f) {
    unsigned u = __builtin_bit_cast(unsigned, f);
    u += 0x7fffu + ((u >> 16) & 1u);        // round-to-nearest-even
    return (unsigned short)(u >> 16);
}

// Wt[kp][o*64 + (i ^ ((o&7)<<3))] = bf16(W[o][i][126-kp])
// (taps reversed -> correlation form; A-side LDS swizzle baked into the
//  global layout so global_load_lds can stage it linearly, m173 pattern)
__global__ void wt_transform(const float* __restrict__ W,
                             unsigned short* __restrict__ Wt) {
    int tid = blockIdx.x * 256 + threadIdx.x;   // o*64 + i, 4096 threads
    int o = tid >> 6, i = tid & 63;
    int j = i ^ ((o & 7) << 3);                 // swizzled dest column
    const float* src = W + tid * KTAPS;         // W[o][i][*], contiguous
    unsigned short* dst = Wt + o * 64 + j;
    for (int kp = 0; kp < KTAPS; ++kp)
        dst[kp * WT_KS] = f2bf(src[126 - kp]);
}

#define GLL16(g, l)                                                        \
    __builtin_amdgcn_global_load_lds(                                      \
        (const __attribute__((address_space(1))) void*)(g),                \
        (__attribute__((address_space(3))) void*)(l), 16, 0, 0)

__global__ __launch_bounds__(256, 2)
void conv_mfma(const float* __restrict__ x,
               const unsigned short* __restrict__ Wt,
               float* __restrict__ y) {
    // xs[w][cin] bf16, XOR-swizzled: halfword = w*64 + (cin ^ ((w&7)<<3))
    __shared__ unsigned short xs[WROWS * 64];   // 49024 B
    __shared__ unsigned short as_[2][WT_KS];    // 16384 B (A double buffer)

    const int tid = threadIdx.x;
    const int bb  = blockIdx.x >> 6;      // batch
    const int tt  = blockIdx.x & 63;      // t-tile
    const int t0  = tt * TN;

    // ---- stage x window [t0-64, t0+319) transposed into LDS (bf16, swizzled)
    {
        const int cin  = tid >> 2;            // 0..63
        const int wseg = (tid & 3) * 96;      // 4 segments of 96 w's
        const float* xrow = x + (bb * CIN + cin) * T_LEN + (t0 - 64);
        for (int j = 0; j < 96; j += 4) {
            const int w = wseg + j;
            const int u = t0 - 64 + w;        // global t index (16B aligned)
            float4v v;
            if (u >= 0 && u + 3 < T_LEN) {
                v = *(const float4v*)(xrow + w);
            } else {
                v.x = (u + 0 >= 0 && u + 0 < T_LEN) ? xrow[w + 0] : 0.f;
                v.y = (u + 1 >= 0 && u + 1 < T_LEN) ? xrow[w + 1] : 0.f;
                v.z = (u + 2 >= 0 && u + 2 < T_LEN) ? xrow[w + 2] : 0.f;
                v.w = (u + 3 >= 0 && u + 3 < T_LEN) ? xrow[w + 3] : 0.f;
            }
            #pragma unroll
            for (int e = 0; e < 4; ++e) {
                const int we = w + e;
                if (we < WROWS) {
                    const float fv = (e == 0) ? v.x : (e == 1) ? v.y : (e == 2) ? v.z : v.w;
                    xs[we * 64 + (cin ^ ((we & 7) << 3))] = f2bf(fv);
                }
            }
        }
    }
    __syncthreads();   // xs ready (full drain here is fine, once)

    const int lane   = tid & 63;
    const int wv     = tid >> 6;          // wave 0..3
    const int l31    = lane & 31;
    const int kg     = lane >> 5;         // K-half (0/1)
    const int twbase = wv * 64;           // wave's 64-t range
    const int h2     = kg ^ (l31 & 7);    // A-frag swizzle term
    const int brow0  = twbase + l31 + 1;  // xs row at k'=0

    // per-wave A staging: 2 x global_load_lds(16B) = 2 KB/wave, 8 KB/block
    auto stageA = [&](int kp, unsigned short* buf) {
        const char* g = (const char*)(Wt + kp * WT_KS) + wv * 2048 + lane * 16;
        char* l = (char*)buf + wv * 2048 + lane * 16;
        GLL16(g, l);
        GLL16(g + 1024, l + 1024);
    };

    stageA(0, as_[0]);
    asm volatile("s_waitcnt vmcnt(0)" ::: "memory");
    __builtin_amdgcn_s_barrier();

    f32x16 acc[2][2] = {};                // [m: o-tile][n: t-tile]

    for (int kp = 0; kp < KTAPS; ++kp) {
        const unsigned short* abuf = as_[kp & 1];
        if (kp + 1 < KTAPS) stageA(kp + 1, as_[(kp & 1) ^ 1]);   // issue early

        const int w0    = brow0 + kp;
        const int h     = kg ^ (w0 & 7);
        const int base0 = w0 * 64;
        #pragma unroll
        for (int cc = 0; cc < 4; ++cc) {           // cin chunks of 16
            const int ach = (((cc << 1) ^ h2) << 3);
            bf16x8 a0 = *(const bf16x8*)(abuf + l31 * 64 + ach);
            bf16x8 a1 = *(const bf16x8*)(abuf + (l31 + 32) * 64 + ach);
            const int coff = (((cc << 1) ^ h) << 3);
            bf16x8 b0 = *(const bf16x8*)(xs + base0 + coff);
            bf16x8 b1 = *(const bf16x8*)(xs + base0 + 2048 + coff);
            acc[0][0] = __builtin_amdgcn_mfma_f32_32x32x16_bf16(a0, b0, acc[0][0], 0, 0, 0);
            acc[0][1] = __builtin_amdgcn_mfma_f32_32x32x16_bf16(a0, b1, acc[0][1], 0, 0, 0);
            acc[1][0] = __builtin_amdgcn_mfma_f32_32x32x16_bf16(a1, b0, acc[1][0], 0, 0, 0);
            acc[1][1] = __builtin_amdgcn_mfma_f32_32x32x16_bf16(a1, b1, acc[1][1], 0, 0, 0);
        }

        // drain late: loads had the whole tap's MFMAs to fly
        asm volatile("s_waitcnt vmcnt(0) lgkmcnt(0)" ::: "memory");
        __builtin_amdgcn_s_barrier();
    }

    // ---- epilogue: D col = lane&31 -> t, row = (r&3)+8*(r>>2)+4*kg -> o
    const int ybase = (bb * COUT) * T_LEN;
    #pragma unroll
    for (int m = 0; m < 2; ++m) {
        #pragma unroll
        for (int n = 0; n < 2; ++n) {
            const int t = t0 + twbase + n * 32 + l31;
            #pragma unroll
            for (int r = 0; r < 16; ++r) {
                const int o = m * 32 + (r & 3) + 8 * (r >> 2) + 4 * kg;
                y[ybase + o * T_LEN + t] = acc[m][n][r];
            }
        }
    }
}

extern "C" void kernel_launch(void* const* d_in, const int* in_sizes, int n_in,
                              void* d_out, int out_size, void* d_ws, size_t ws_size,
                              hipStream_t stream) {
    const float* x = (const float*)d_in[0];
    const float* W = (const float*)d_in[1];
    float* yout = (float*)d_out;
    unsigned short* Wt = (unsigned short*)d_ws;   // 127*4096*2 B ~= 1 MB

    wt_transform<<<16, 256, 0, stream>>>(W, Wt);

    const int grid = 8 * (T_LEN / TN);            // 512 blocks
    conv_mfma<<<grid, 256, 0, stream>>>(x, Wt, yout);
}